// Round 1
// baseline (638.853 us; speedup 1.0000x reference)
//
#include <hip/hip_runtime.h>

#define TL  2048
#define NB  4096
#define INSZ 8
#define HID 10

__device__ __forceinline__ float rcp_(float x) { return __builtin_amdgcn_rcpf(x); }
__device__ __forceinline__ float sig_(float x) { return rcp_(1.0f + __expf(-x)); }
__device__ __forceinline__ float tanh_(float x) { return 1.0f - 2.0f * rcp_(__expf(2.0f * x) + 1.0f); }

// Decomposition: lane = 16*chain_sub + j16. Each wave owns 4 batch chains
// (lanes n*16..n*16+15). Lane (n, j<10) owns hidden unit j of chain n:
// computes gate rows {j, 10+j, 20+j, 30+j} (72 FMA/step), updates c_j, h_j
// locally. h broadcast across the 16 lanes via __shfl (wave-synchronous, no
// barriers). j16 in 10..15 are padding lanes (compute garbage, never read).
// grid = 1024 blocks x 64 thr = 1024 waves = 1 wave/SIMD on 256 CUs.
__global__ void __launch_bounds__(64) lstm_fused(
    const float* __restrict__ x,
    const float* __restrict__ h0,
    const float* __restrict__ c0,
    const float* __restrict__ Wih,
    const float* __restrict__ Whh,
    const float* __restrict__ bih,
    const float* __restrict__ bhh,
    const float* __restrict__ Wfc,
    const float* __restrict__ bfc,
    float* __restrict__ out)
{
    const int lane = threadIdx.x;
    const int j16  = lane & 15;
    const int grp  = lane >> 4;
    const int n    = (blockIdx.x << 2) + grp;
    const int j    = (j16 < HID) ? j16 : 0;   // clamp padding lanes to a valid row
    const int src  = lane & 48;               // base lane of this chain's group

    // loop-invariant weights in VGPRs: 4 rows x (8 + 10) + bias = 76 regs
    float wih[4][INSZ], whh[4][HID], bias[4];
#pragma unroll
    for (int r = 0; r < 4; ++r) {
        const int row = r * HID + j;
#pragma unroll
        for (int i = 0; i < INSZ; ++i) wih[r][i] = Wih[row * INSZ + i];
#pragma unroll
        for (int k = 0; k < HID; ++k) whh[r][k] = Whh[row * HID + k];
        bias[r] = bih[row] + bhh[row];
    }

    float cst = c0[n * HID + j];
    float hst = h0[n * HID + j];

    const size_t xs = (size_t)NB * INSZ;      // floats per timestep slab
    const float* xp = x + (size_t)n * INSZ;

#define XLD(dst0, dst1, tt) do { \
        const float* p_ = xp + (size_t)(tt) * xs; \
        dst0 = *(const float4*)(p_); \
        dst1 = *(const float4*)(p_ + 4); \
    } while (0)

#define STEP(X0, X1) do { \
        float hv[HID]; \
        _Pragma("unroll") \
        for (int k = 0; k < HID; ++k) hv[k] = __shfl(hst, src + k, 64); \
        const float xv[INSZ] = {X0.x, X0.y, X0.z, X0.w, X1.x, X1.y, X1.z, X1.w}; \
        float a0 = bias[0], a1 = bias[1], a2 = bias[2], a3 = bias[3]; \
        _Pragma("unroll") \
        for (int i = 0; i < INSZ; ++i) { \
            a0 += wih[0][i] * xv[i]; a1 += wih[1][i] * xv[i]; \
            a2 += wih[2][i] * xv[i]; a3 += wih[3][i] * xv[i]; \
        } \
        _Pragma("unroll") \
        for (int k = 0; k < HID; ++k) { \
            a0 += whh[0][k] * hv[k]; a1 += whh[1][k] * hv[k]; \
            a2 += whh[2][k] * hv[k]; a3 += whh[3][k] * hv[k]; \
        } \
        const float ig = sig_(a0); \
        const float fg = sig_(a1); \
        const float gg = tanh_(a2); \
        const float og = sig_(a3); \
        cst = fg * cst + ig * gg; \
        hst = og * tanh_(cst); \
    } while (0)

    // 8-step unrolled ping-pong with register prefetch of x (4-7 steps ahead,
    // covers ~900cy HBM latency at ~250cy/step with only 1 wave/SIMD).
    float4 A0,A1,B0,B1,C0,C1,D0,D1, E0,E1,F0,F1,G0,G1,H0,H1;
    XLD(A0,A1,0); XLD(B0,B1,1); XLD(C0,C1,2); XLD(D0,D1,3);

    for (int t = 0; t < TL; t += 8) {
        XLD(E0,E1,t+4); XLD(F0,F1,t+5); XLD(G0,G1,t+6); XLD(H0,H1,t+7);
        STEP(A0,A1); STEP(B0,B1); STEP(C0,C1); STEP(D0,D1);
        const int t8 = t + 8;
        const int ta = (t8     < TL) ? t8     : 0;  // clamped dummy reload on last iter
        const int tb = (t8 + 1 < TL) ? t8 + 1 : 0;
        const int tc = (t8 + 2 < TL) ? t8 + 2 : 0;
        const int td = (t8 + 3 < TL) ? t8 + 3 : 0;
        XLD(A0,A1,ta); XLD(B0,B1,tb); XLD(C0,C1,tc); XLD(D0,D1,td);
        STEP(E0,E1); STEP(F0,F1); STEP(G0,G1); STEP(H0,H1);
    }

#undef STEP
#undef XLD

    // epilogue: y = h @ W_fc.T + b_fc, then dump h and c
    float hv[HID];
#pragma unroll
    for (int k = 0; k < HID; ++k) hv[k] = __shfl(hst, src + k, 64);

    if (j16 < INSZ) {
        float acc = bfc[j16];
#pragma unroll
        for (int k = 0; k < HID; ++k) acc += Wfc[j16 * HID + k] * hv[k];
        out[n * INSZ + j16] = acc;
    }
    if (j16 < HID) {
        out[NB * INSZ + n * HID + j16] = hst;
        out[NB * INSZ + NB * HID + n * HID + j16] = cst;
    }
}

extern "C" void kernel_launch(void* const* d_in, const int* in_sizes, int n_in,
                              void* d_out, int out_size, void* d_ws, size_t ws_size,
                              hipStream_t stream) {
    const float* x   = (const float*)d_in[0];
    const float* h0  = (const float*)d_in[1];
    const float* c0  = (const float*)d_in[2];
    const float* Wih = (const float*)d_in[3];
    const float* Whh = (const float*)d_in[4];
    const float* bih = (const float*)d_in[5];
    const float* bhh = (const float*)d_in[6];
    const float* Wfc = (const float*)d_in[7];
    const float* bfc = (const float*)d_in[8];
    float* out = (float*)d_out;

    lstm_fused<<<NB / 4, 64, 0, stream>>>(x, h0, c0, Wih, Whh, bih, bhh, Wfc, bfc, out);
}